// Round 12
// baseline (107.237 us; speedup 1.0000x reference)
//
#include <hip/hip_runtime.h>
#include <cmath>

#define NB 128     // batch
#define CC 1024    // classes
#define CAP 64     // max nnz per row of R (expected ~11, P(>63) negligible)
#define NBUCKET 32 // contention spreading for the two global accumulators

// ---------------------------------------------------------------------------
// Mono-kernel: one block per class i (1024 blocks x 256 threads).
// Self-sufficient per block -> no inter-kernel dependencies:
//   Phase 1: scan R row i (float4), build CSR row in LDS (~11 nnz).
//   Phase 2: for n = tx&127, k-loop split even/odd across thread halves:
//            p = sigmoid(h[n,j]) computed on the fly (bit-identical formula),
//            m  = max v*p ; mp = max over y[n,j]==1 of v*p.
//            (yf in {0,1} => v*(p*yf) is exactly v*p or 0: matches reference.)
//   Phase 3: combine halves via LDS; per-n: h* = y ? mp : m; write mcm=m to
//            out+1; block-local deterministic reduce of dice I/card/present
//            and clamped-log BCE; 2 bucketed atomicAdds per block.
//   Epilogue: fence + ticket; last block sums buckets (agent-scope loads)
//            and writes the loss scalar. Replaces the finalize dispatch.
// ---------------------------------------------------------------------------
__global__ __launch_bounds__(256) void mono_kernel(
        const float* __restrict__ R, const float* __restrict__ h,
        const int* __restrict__ y, float* __restrict__ mcm_out, // = out+1
        float* __restrict__ out0,                                // loss scalar
        float* __restrict__ diceB, float* __restrict__ bceB,     // [NBUCKET]
        int* __restrict__ ticket) {
    const int i = blockIdx.x, tx = threadIdx.x;

    __shared__ int   s_cnt;
    __shared__ int   s_cols[CAP];
    __shared__ float s_vals[CAP];
    __shared__ float s_m[256], s_mp[256];
    __shared__ float s_red[4][3];
    __shared__ int   s_last;

    // ---- Phase 1: CSR row i of R ----
    if (tx == 0) s_cnt = 0;
    __syncthreads();
    {
        const float4 v4 = ((const float4*)(R + (size_t)i * CC))[tx];
        const int j0 = tx * 4;
        #pragma unroll
        for (int u = 0; u < 4; ++u) {
            const float v = (u == 0) ? v4.x : (u == 1) ? v4.y : (u == 2) ? v4.z : v4.w;
            if (v != 0.0f) {
                const int pos = atomicAdd(&s_cnt, 1);
                if (pos < CAP) { s_cols[pos] = j0 + u; s_vals[pos] = v; }
            }
        }
    }
    __syncthreads();
    const int rc = min(s_cnt, CAP);

    // ---- Phase 2: sparse max-gather, sigmoid on the fly ----
    const int n = tx & 127;
    const float* __restrict__ hrow = h + n * CC;
    const int*   __restrict__ yrow = y + n * CC;
    float m = 0.0f, mp = 0.0f;
    for (int k = (tx >> 7); k < rc; k += 2) {     // halves take even/odd k
        const int   j  = s_cols[k];
        const float v  = s_vals[k];
        const float pj = 1.0f / (1.0f + expf(-hrow[j]));
        const float vp = v * pj;
        m = fmaxf(m, vp);
        if (yrow[j]) mp = fmaxf(mp, vp);
    }
    s_m[tx] = m; s_mp[tx] = mp;
    __syncthreads();

    // ---- Phase 3: per-n epilogue + block-local reductions ----
    float I = 0.0f, card = 0.0f, bce = 0.0f;
    if (tx < 128) {
        m  = fmaxf(s_m[tx],  s_m[tx + 128]);
        mp = fmaxf(s_mp[tx], s_mp[tx + 128]);
        const int   yv = yrow[i];                 // y[n,i]
        const float yf = (float)yv;
        const float hv = yv ? mp : m;             // h_star
        mcm_out[n * CC + i] = m;                  // mcm on raw probs
        I    = yv ? hv : 0.0f;
        card = hv + yf;
        float lg = yv ? logf(hv) : log1pf(-hv);
        bce  = fmaxf(lg, -100.0f);
    }
    // reduce over all 4 waves (waves 2,3 contribute zeros)
    #pragma unroll
    for (int off = 32; off > 0; off >>= 1) {
        I    += __shfl_down(I, off);
        card += __shfl_down(card, off);
        bce  += __shfl_down(bce, off);
    }
    const int wid = tx >> 6, lane = tx & 63;
    if (lane == 0) { s_red[wid][0] = I; s_red[wid][1] = card; s_red[wid][2] = bce; }
    __syncthreads();

    if (tx == 0) {
        const float It = s_red[0][0] + s_red[1][0] + s_red[2][0] + s_red[3][0];
        const float Ct = s_red[0][1] + s_red[1][1] + s_red[2][1] + s_red[3][1];
        const float Bt = s_red[0][2] + s_red[1][2] + s_red[2][2] + s_red[3][2];
        // present <=> It > 0 (exact: y=1 contributes h* >= p > 0 via R diagonal;
        // block-local sum is exactly 0.0 when no y=1).
        const float dice = (It > 0.0f) ? (1.0f - 2.0f * It / fmaxf(Ct, 1e-7f)) : 0.0f;
        atomicAdd(diceB + (i & (NBUCKET - 1)), dice);
        atomicAdd(bceB  + (i & (NBUCKET - 1)), Bt);
        __threadfence();                           // bucket updates visible
        s_last = (atomicAdd(ticket, 1) == gridDim.x - 1);
    }
    __syncthreads();

    // ---- Epilogue: last block combines buckets and writes the loss ----
    if (s_last && tx == 0) {
        __threadfence();                           // acquire side
        float ds = 0.0f, bs = 0.0f;
        #pragma unroll
        for (int b = 0; b < NBUCKET; ++b) {
            ds += __hip_atomic_load(diceB + b, __ATOMIC_RELAXED, __HIP_MEMORY_SCOPE_AGENT);
            bs += __hip_atomic_load(bceB  + b, __ATOMIC_RELAXED, __HIP_MEMORY_SCOPE_AGENT);
        }
        out0[0] = ds / (float)CC - bs / (float)(NB * CC);
    }
}

// ---------------------------------------------------------------------------
extern "C" void kernel_launch(void* const* d_in, const int* in_sizes, int n_in,
                              void* d_out, int out_size, void* d_ws, size_t ws_size,
                              hipStream_t stream) {
    const float* h = (const float*)d_in[0];
    const int*   y = (const int*)d_in[1];
    const float* R = (const float*)d_in[2];
    float* out = (float*)d_out;          // out[0]=loss, out[1..]=mcm (N,C)

    // ws: diceB[32] | bceB[32] | ticket  (260 bytes, zeroed every call)
    float* diceB  = (float*)d_ws;
    float* bceB   = diceB + NBUCKET;
    int*   ticket = (int*)(bceB + NBUCKET);

    hipMemsetAsync(d_ws, 0, (2 * NBUCKET + 1) * sizeof(float), stream);
    mono_kernel<<<CC, 256, 0, stream>>>(R, h, y, out + 1, out,
                                        diceB, bceB, ticket);
}